// Round 6
// baseline (887.208 us; speedup 1.0000x reference)
//
#include <hip/hip_runtime.h>
#include <hip/hip_bf16.h>
#include <cstdint>

// ---------------------------------------------------------------------------
// RecurrentResourceActionHead — fused single-pass implementation.
//
// Key algebra:
//  * x = [main_inputs, output]; x@W1 = main@W1[0:256] (iteration-invariant,
//    computed ONCE) + counts@W1[256:262] (rank<=5 correction per iteration).
//  * h is unobserved: logits = relu(LN)@(W2@Wd) + (b2@Wd + bd). W2@Wd (128x6)
//    precomputed by prep_kernel.
//
// R4 lesson: (256,2) caps VGPR at 128; a 248-reg working set spilled 2.4 GB.
// R5 lesson: (256,1) -> 248 VGPR, no spills, but 2 waves/SIMD -> latency-
// bound (VALUBusy 45%, dur 386us vs 109us FMA floor).
// R6: shrink the working set to ~110 regs (B-dbuf 32 regs, gamma/beta/bdp in
// LDS, msk eliminated, loads post-GEMM) and take (256,2) -> 128 VGPR,
// 4 waves/SIMD, 4 blocks/CU. Tripwire: WRITE_SIZE >> 20MB means spills.
// ---------------------------------------------------------------------------

#define NROW 64
#define NBLK 2048            // 131072 / 64

// LDS float offsets (flat).
#define OFF_AT0  0           // AT[32][68] transposed X tile, buffer 0  (2176)
#define OFF_AT1  2176        // AT buffer 1                             (2176)
#define OFF_REDL 4352        // redL[4][64][3]  (sum, sumsq)            (768)
#define OFF_REDP 5120        // redP[4][64][9]  (6 used)                (2304)
#define OFF_EV   7424        // ev[4] wave entropy partials             (4)
#define OFF_W1B  7428        // W1bot[6][132]                           (792)
#define OFF_WC   8220        // skewed Wc: c*8 + (c>>3) + l             (1040)
#define OFF_CNT  9260        // cnt[64][7]                              (448)
#define OFF_GM   9708        // gamma[128]
#define OFF_BT   9836        // beta[128]
#define OFF_BDP  9964        // bdp[6]
#define LDS_N    9970        // 39880 B -> 4 blocks/CU (159.7 KB of 160)

// d_out layout (floats): output[B][6], modes[B][4], lp[B], ent_mean[1]
#define OUT_MODES 786432
#define OUT_LP    1310720
#define OUT_ENT   1441792

// workspace float offsets
#define WS_WC  0             // 128*6
#define WS_BDP 768           // 6
#define WS_EP  1024          // 2048 block entropy partials

// ---------------------------------------------------------------------------
__global__ __launch_bounds__(256) void prep_kernel(
    const float* __restrict__ W2, const float* __restrict__ Wd,
    const float* __restrict__ b2, const float* __restrict__ bd,
    float* __restrict__ ws) {
  const int t = threadIdx.x;
  if (t < 128) {
    float a0 = 0.f, a1 = 0.f, a2 = 0.f, a3 = 0.f, a4 = 0.f, a5 = 0.f;
    for (int j = 0; j < 128; ++j) {
      const float w = W2[t * 128 + j];
      const float* wd = Wd + j * 6;
      a0 = fmaf(w, wd[0], a0); a1 = fmaf(w, wd[1], a1); a2 = fmaf(w, wd[2], a2);
      a3 = fmaf(w, wd[3], a3); a4 = fmaf(w, wd[4], a4); a5 = fmaf(w, wd[5], a5);
    }
    float* o = ws + WS_WC + t * 6;
    o[0] = a0; o[1] = a1; o[2] = a2; o[3] = a3; o[4] = a4; o[5] = a5;
  } else if (t < 134) {
    const int l = t - 128;
    float s = 0.f;
    for (int j = 0; j < 128; ++j) s = fmaf(b2[j], Wd[j * 6 + l], s);
    ws[WS_BDP + l] = bd[l] + s;
  }
}

// ---------------------------------------------------------------------------
__global__ __launch_bounds__(256, 2) void fused_kernel(
    const float* __restrict__ X,    // [B][256]
    const float* __restrict__ CRES, // [B][6]
    const int*   __restrict__ ACT,  // [B][4]
    const float* __restrict__ HTM,  // [16]
    const int*   __restrict__ PHA,  // [B]
    const float* __restrict__ W1,   // [262][128]
    const float* __restrict__ B1,   // [128]
    const float* __restrict__ G,    // [128]
    const float* __restrict__ BETA, // [128]
    const float* __restrict__ WS,   // workspace (Wc, bdp)
    float* __restrict__ out,
    float* __restrict__ EP) {       // [NBLK] entropy partials
  __shared__ __align__(16) float lds[LDS_N];

  const int t    = threadIdx.x;
  const int tr   = t & 15;          // GEMM: row group (4 rows each)
  const int tc   = t >> 4;          // GEMM: col group (8 cols each)
  const int r0   = tr * 4;
  const int c0   = tc * 8;
  const int wv   = t >> 6;          // wave 0..3
  const int row  = t >> 2;          // softmax layout: local row 0..63
  const int part = t & 3;           // softmax layout: 4 lanes per row
  const long grow = (long)blockIdx.x * NROW + row;

  // ---- persistent small LDS staging (visible after first barrier) ----
  if (t < 192) {                    // W1 bottom rows (output-part of concat)
    const int j = t >> 5, c = (t & 31) * 4;
    *(float4*)&lds[OFF_W1B + j * 132 + c] =
        *(const float4*)(W1 + (size_t)(256 + j) * 128 + c);
  } else {                          // zero the counts buffer (rows 0..63)
    const int rr = t - 192;
#pragma unroll
    for (int j = 0; j < 7; ++j) lds[OFF_CNT + rr * 7 + j] = 0.f;
  }
  if (t < 128) {                    // skewed Wc + gamma/beta broadcast copies
#pragma unroll
    for (int l = 0; l < 6; ++l)
      lds[OFF_WC + t * 8 + (t >> 3) + l] = WS[WS_WC + t * 6 + l];
    lds[OFF_GM + t] = G[t];
    lds[OFF_BT + t] = BETA[t];
  } else if (t < 134) {
    lds[OFF_BDP + (t - 128)] = WS[WS_BDP + (t - 128)];
  }

  // ---- GEMM helpers ----
  const float* xrow = X + (size_t)grow * 256;
  const int xoff = part * 8;

  auto load_x = [&](int th, float4& x0, float4& x1) {
    x0 = *(const float4*)(xrow + th * 32 + xoff);
    x1 = *(const float4*)(xrow + th * 32 + xoff + 4);
  };
  // AT stores: transpose X into AT[kk][row]; 4-way bank aliasing on the
  // scalar stores is unavoidable and cheap (8 stores/thread/tile).
  auto write_tile = [&](int atbase, const float4& x0, const float4& x1) {
    float* d = &lds[atbase + row];
    d[(xoff + 0) * 68] = x0.x; d[(xoff + 1) * 68] = x0.y;
    d[(xoff + 2) * 68] = x0.z; d[(xoff + 3) * 68] = x0.w;
    d[(xoff + 4) * 68] = x1.x; d[(xoff + 5) * 68] = x1.y;
    d[(xoff + 6) * 68] = x1.z; d[(xoff + 7) * 68] = x1.w;
  };

  float acc[4][8];
  {
    const float4 o0 = *(const float4*)(B1 + c0);
    const float4 o1 = *(const float4*)(B1 + c0 + 4);
    const float bi[8] = {o0.x, o0.y, o0.z, o0.w, o1.x, o1.y, o1.z, o1.w};
#pragma unroll
    for (int m = 0; m < 4; ++m)
#pragma unroll
      for (int cc = 0; cc < 8; ++cc) acc[m][cc] = bi[cc];
  }

  // B group = 2 kk-steps of this thread's 8 cols (4 float4 = 16 VGPR).
  // 16 lanes share each address -> broadcast-coalesced from L1/L2-hot W1.
  auto loadg = [&](const float* wb, int g, float4 (&Bb)[4]) {
    const float* p = wb + g * 256;
    Bb[0] = *(const float4*)(p + 0);   Bb[1] = *(const float4*)(p + 4);
    Bb[2] = *(const float4*)(p + 128); Bb[3] = *(const float4*)(p + 132);
  };
  auto compg = [&](int atbase, int g, const float4 (&Bb)[4]) {
#pragma unroll
    for (int q = 0; q < 2; ++q) {
      const float4 a4 = *(const float4*)&lds[atbase + (g * 2 + q) * 68 + r0];
      const float av[4] = {a4.x, a4.y, a4.z, a4.w};
      const float4 bl = Bb[2 * q], bh = Bb[2 * q + 1];
      const float bv[8] = {bl.x, bl.y, bl.z, bl.w, bh.x, bh.y, bh.z, bh.w};
#pragma unroll
      for (int m = 0; m < 4; ++m)
#pragma unroll
        for (int cc = 0; cc < 8; ++cc)
          acc[m][cc] = fmaf(av[m], bv[cc], acc[m][cc]);
    }
  };
  // 32 kk = 16 groups; 2-buffer rotation, each load issued 2 groups ahead
  // of its use (~280 issue-cycles at 1 wave; x4 waves/SIMD covers L2).
  auto compute_tile = [&](int atbase, int ti) {
    const float* wb = W1 + (size_t)(ti * 32) * 128 + c0;
    float4 bA[4], bB[4];
    loadg(wb, 0, bA);  loadg(wb, 1, bB);
    compg(atbase, 0, bA);  loadg(wb, 2, bA);
    compg(atbase, 1, bB);  loadg(wb, 3, bB);
    compg(atbase, 2, bA);  loadg(wb, 4, bA);
    compg(atbase, 3, bB);  loadg(wb, 5, bB);
    compg(atbase, 4, bA);  loadg(wb, 6, bA);
    compg(atbase, 5, bB);  loadg(wb, 7, bB);
    compg(atbase, 6, bA);  loadg(wb, 8, bA);
    compg(atbase, 7, bB);  loadg(wb, 9, bB);
    compg(atbase, 8, bA);  loadg(wb, 10, bA);
    compg(atbase, 9, bB);  loadg(wb, 11, bB);
    compg(atbase, 10, bA); loadg(wb, 12, bA);
    compg(atbase, 11, bB); loadg(wb, 13, bB);
    compg(atbase, 12, bA); loadg(wb, 14, bA);
    compg(atbase, 13, bB); loadg(wb, 15, bB);
    compg(atbase, 14, bA);
    compg(atbase, 15, bB);
  };

  // ---- prologue: X tile0 -> AT0; tile1 prefetched to registers ----
  float4 xa0, xa1, xb0, xb1;
  load_x(0, xa0, xa1);
  load_x(1, xb0, xb1);
  write_tile(OFF_AT0, xa0, xa1);
  __syncthreads();                  // AT0 + small staging visible

  // ---- GEMM: 8 tiles, LDS double-buffered A, 1 barrier per tile ----
#pragma unroll 1
  for (int p = 0; p < 4; ++p) {
    write_tile(OFF_AT1, xb0, xb1);
    if (p < 3) load_x(2 * p + 2, xa0, xa1);
    compute_tile(OFF_AT0, 2 * p);
    __syncthreads();                // AT1 ready; AT0 dead
    if (p < 3) {
      write_tile(OFF_AT0, xa0, xa1);
      load_x(2 * p + 3, xb0, xb1);
    }
    compute_tile(OFF_AT1, 2 * p + 1);
    __syncthreads();                // AT0 ready for next p (or GEMM done)
  }

  // ---- post-GEMM per-row state (latency overlapped across 4 blocks/CU) ----
  float cr[6], cnt[6] = {0.f, 0.f, 0.f, 0.f, 0.f, 0.f};
  float m0f;                        // iteration-0 slot-0 mask
  {
    const float2* cp = (const float2*)(CRES + grow * 6);
    const float2 ca = cp[0], cb = cp[1], cc2 = cp[2];
    cr[0] = ca.x; cr[1] = ca.y; cr[2] = cb.x;
    cr[3] = cb.y; cr[4] = cc2.x; cr[5] = cc2.y;
    const float s = cr[0] + cr[1] + cr[2] + cr[3] + cr[4] + cr[5];
    m0f = (s == 0.f) ? 1.f : 0.f;
  }
  const int4 act = ((const int4*)ACT)[grow];
  const float hm = HTM[PHA[grow]];
  float lpsum = 0.f, entsum = 0.f;
  float modesf[4];

  // ---- 4 recurrent iterations (fully unrolled, static indexing only) ----
#pragma unroll
  for (int it = 0; it < 4; ++it) {
    // 1) hpre = base + counts @ W1bot
    float hp[4][8];
#pragma unroll
    for (int m = 0; m < 4; ++m)
#pragma unroll
      for (int cc = 0; cc < 8; ++cc) hp[m][cc] = acc[m][cc];
    if (it > 0) {
#pragma unroll
      for (int j = 1; j < 6; ++j) {
        const float4 w0 = *(const float4*)&lds[OFF_W1B + j * 132 + c0];
        const float4 w4 = *(const float4*)&lds[OFF_W1B + j * 132 + c0 + 4];
        const float wv8[8] = {w0.x, w0.y, w0.z, w0.w, w4.x, w4.y, w4.z, w4.w};
#pragma unroll
        for (int m = 0; m < 4; ++m) {
          const float cj = lds[OFF_CNT + (r0 + m) * 7 + j];
#pragma unroll
          for (int cc = 0; cc < 8; ++cc)
            hp[m][cc] = fmaf(cj, wv8[cc], hp[m][cc]);
        }
      }
    }

    // 2) LayerNorm stats, single pass (var = E[x^2] - mu^2)
    float mu[4], rs[4];
    {
      float sx[4], sq[4];
#pragma unroll
      for (int m = 0; m < 4; ++m) {
        float a = 0.f, b = 0.f;
#pragma unroll
        for (int cc = 0; cc < 8; ++cc) {
          a += hp[m][cc];
          b = fmaf(hp[m][cc], hp[m][cc], b);
        }
        a += __shfl_xor(a, 16, 64); a += __shfl_xor(a, 32, 64);
        b += __shfl_xor(b, 16, 64); b += __shfl_xor(b, 32, 64);
        sx[m] = a; sq[m] = b;
      }
      if ((tc & 3) == 0) {
#pragma unroll
        for (int m = 0; m < 4; ++m) {
          lds[OFF_REDL + (wv * 64 + r0 + m) * 3 + 0] = sx[m];
          lds[OFF_REDL + (wv * 64 + r0 + m) * 3 + 1] = sq[m];
        }
      }
    }
    __syncthreads();
#pragma unroll
    for (int m = 0; m < 4; ++m) {
      float a = 0.f, b = 0.f;
#pragma unroll
      for (int w = 0; w < 4; ++w) {
        a += lds[OFF_REDL + (w * 64 + r0 + m) * 3 + 0];
        b += lds[OFF_REDL + (w * 64 + r0 + m) * 3 + 1];
      }
      mu[m] = a * (1.f / 128.f);
      const float var = b * (1.f / 128.f) - mu[m] * mu[m];
      rs[m] = 1.f / sqrtf(var + 1e-5f);
    }

    // 3) relu(LN) -> partial logits. cc-outer: gamma/beta/Wc LDS reads
    //    are shared across the 4 m's (64 scalar reads/iter, broadcast).
    float pl[4][6];
#pragma unroll
    for (int m = 0; m < 4; ++m)
#pragma unroll
      for (int l = 0; l < 6; ++l) pl[m][l] = 0.f;
#pragma unroll
    for (int cc = 0; cc < 8; ++cc) {
      const float gmv = lds[OFF_GM + c0 + cc];
      const float btv = lds[OFF_BT + c0 + cc];
      const float* wp = &lds[OFF_WC + (c0 + cc) * 8 + tc];
      const float w0 = wp[0], w1 = wp[1], w2 = wp[2];
      const float w3 = wp[3], w4 = wp[4], w5 = wp[5];
#pragma unroll
      for (int m = 0; m < 4; ++m) {
        float v = fmaf((hp[m][cc] - mu[m]) * rs[m], gmv, btv);
        v = fmaxf(v, 0.f);
        pl[m][0] = fmaf(v, w0, pl[m][0]);
        pl[m][1] = fmaf(v, w1, pl[m][1]);
        pl[m][2] = fmaf(v, w2, pl[m][2]);
        pl[m][3] = fmaf(v, w3, pl[m][3]);
        pl[m][4] = fmaf(v, w4, pl[m][4]);
        pl[m][5] = fmaf(v, w5, pl[m][5]);
      }
    }
#pragma unroll
    for (int m = 0; m < 4; ++m)
#pragma unroll
      for (int l = 0; l < 6; ++l) {
        float a = pl[m][l];
        a += __shfl_xor(a, 16, 64); a += __shfl_xor(a, 32, 64);
        pl[m][l] = a;
      }
    {
      const int q = tc & 3;
#pragma unroll
      for (int mm = 0; mm < 4; ++mm)
        if (q == mm) {
#pragma unroll
          for (int l = 0; l < 6; ++l)
            lds[OFF_REDP + (wv * 64 + r0 + mm) * 9 + l] = pl[mm][l];
        }
    }
    __syncthreads();

    // 4) per-row masked log-softmax (softmax layout, 4 redundant lanes/row)
    float lg[6];
#pragma unroll
    for (int l = 0; l < 6; ++l) {
      float a = lds[OFF_REDP + row * 9 + l];
      a += lds[OFF_REDP + (64 + row) * 9 + l];
      a += lds[OFF_REDP + (128 + row) * 9 + l];
      a += lds[OFF_REDP + (192 + row) * 9 + l];
      lg[l] = a + lds[OFF_BDP + l];
    }
    float ml[6];
    ml[0] = (it == 0) ? ((m0f > 0.f) ? lg[0] : -1000000000.0f) : lg[0];
#pragma unroll
    for (int l = 1; l < 6; ++l)
      ml[l] = (cr[l] > 0.f) ? lg[l] : -1000000000.0f;
    float mx = ml[0];
    int bi = 0;
#pragma unroll
    for (int l = 1; l < 6; ++l)
      if (ml[l] > mx) { mx = ml[l]; bi = l; }   // strict > : first-max, as jnp
    modesf[it] = (float)bi;
    float sh[6], e[6], se = 0.f;
#pragma unroll
    for (int l = 0; l < 6; ++l) {
      sh[l] = ml[l] - mx;
      e[l] = __expf(sh[l]);
      se += e[l];
    }
    const float lse = __logf(se);
    const float ise = 1.f / se;
    float ent = 0.f;
#pragma unroll
    for (int l = 0; l < 6; ++l)
      ent -= (e[l] * ise) * (sh[l] - lse);   // -(p * logp); masked -> exact 0
    const int a = (it == 0) ? act.x : (it == 1) ? act.y : (it == 2) ? act.z : act.w;
    float lp = -lse;
#pragma unroll
    for (int l = 0; l < 6; ++l)
      if (l == a) lp += sh[l];
    if (it > 0) {
      const int ap = (it == 1) ? act.x : (it == 2) ? act.y : act.z;
      const float mp = (ap > 0) ? 1.f : 0.f;
      lp *= mp;
      ent *= mp;
    }
    lpsum += lp;
    entsum += ent;

    // 5) state update (exact integer arithmetic; static indexing)
#pragma unroll
    for (int l = 0; l < 6; ++l) {
      if (l == a) {
        if (l > 0) cnt[l] += 1.f;
        cr[l] = fmaxf(cr[l] - 1.f, 0.f);
      }
    }
    if (part == 0 && it < 3) {
#pragma unroll
      for (int j = 1; j < 6; ++j) lds[OFF_CNT + row * 7 + j] = cnt[j];
    }
    __syncthreads();
  }

  // ---- final outputs ----
  if (part == 0) {
    *(float2*)(out + grow * 6) = make_float2(cnt[0], cnt[1]);
  } else if (part == 1) {
    *(float2*)(out + grow * 6 + 2) = make_float2(cnt[2], cnt[3]);
  } else if (part == 2) {
    *(float2*)(out + grow * 6 + 4) = make_float2(cnt[4], cnt[5]);
  }
  if (part == 0) {
    *(float4*)(out + OUT_MODES + grow * 4) =
        make_float4(modesf[0], modesf[1], modesf[2], modesf[3]);
    out[OUT_LP + grow] = lpsum * hm;
  }
  // deterministic per-block entropy partial
  float ev = (part == 0) ? entsum * hm : 0.f;
#pragma unroll
  for (int off = 1; off < 64; off <<= 1) ev += __shfl_xor(ev, off, 64);
  if ((t & 63) == 0) lds[OFF_EV + wv] = ev;
  __syncthreads();
  if (t == 0)
    EP[blockIdx.x] =
        lds[OFF_EV] + lds[OFF_EV + 1] + lds[OFF_EV + 2] + lds[OFF_EV + 3];
}

// ---------------------------------------------------------------------------
__global__ __launch_bounds__(256) void ent_reduce(const float* __restrict__ EP,
                                                  float* __restrict__ out) {
  const int t = threadIdx.x;
  float s = 0.f;
#pragma unroll
  for (int i = 0; i < 8; ++i) s += EP[t + 256 * i];
#pragma unroll
  for (int off = 1; off < 64; off <<= 1) s += __shfl_xor(s, off, 64);
  __shared__ float w[4];
  if ((t & 63) == 0) w[t >> 6] = s;
  __syncthreads();
  if (t == 0)
    out[OUT_ENT] = (w[0] + w[1] + w[2] + w[3]) * (1.f / 131072.f);
}

// ---------------------------------------------------------------------------
extern "C" void kernel_launch(void* const* d_in, const int* in_sizes, int n_in,
                              void* d_out, int out_size, void* d_ws, size_t ws_size,
                              hipStream_t stream) {
  (void)in_sizes; (void)n_in; (void)out_size; (void)ws_size;
  const float* main_inputs = (const float*)d_in[0];
  const float* cur_res     = (const float*)d_in[1];
  const int*   actions     = (const int*)d_in[2];
  const float* htm         = (const float*)d_in[3];
  const int*   pha         = (const int*)d_in[4];
  const float* W1          = (const float*)d_in[5];
  const float* b1          = (const float*)d_in[6];
  const float* gamma       = (const float*)d_in[7];
  const float* beta        = (const float*)d_in[8];
  const float* W2          = (const float*)d_in[9];
  const float* b2          = (const float*)d_in[10];
  const float* Wd          = (const float*)d_in[11];
  const float* bd          = (const float*)d_in[12];
  float* out = (float*)d_out;
  float* ws  = (float*)d_ws;

  prep_kernel<<<1, 256, 0, stream>>>(W2, Wd, b2, bd, ws);
  fused_kernel<<<NBLK, 256, 0, stream>>>(main_inputs, cur_res, actions, htm,
                                         pha, W1, b1, gamma, beta, ws, out,
                                         ws + WS_EP);
  ent_reduce<<<1, 256, 0, stream>>>(ws + WS_EP, out);
}

// Round 7
// 405.441 us; speedup vs baseline: 2.1883x; 2.1883x over previous
//
#include <hip/hip_runtime.h>
#include <hip/hip_bf16.h>
#include <cstdint>

// ---------------------------------------------------------------------------
// RecurrentResourceActionHead — fused single-pass implementation.
//
// Key algebra:
//  * x = [main_inputs, output]; x@W1 = main@W1[0:256] (iteration-invariant,
//    computed ONCE) + counts@W1[256:262] (rank<=5 correction per iteration).
//  * h is unobserved: logits = relu(LN)@(W2@Wd) + (b2@Wd + bd). W2@Wd (128x6)
//    precomputed by prep_kernel.
//
// R4: (256,2) caps VGPR at 128; 248-reg demand spilled 2.4 GB.
// R5: (256,1) -> 248 VGPR, no spills, 2 waves/SIMD, latency-bound 386us.
// R6: shrank buffers but kept a fully-unrolled inner loop -> scheduler
//     hoisted loads into 3-4 in-flight buffer generations -> spilled again
//     at the 128 cap (WRITE_SIZE 1.54 GB). Lesson: the SCHEDULE, not the
//     source buffer count, sets register pressure.
// R7: pin the schedule structurally — B-prefetch rotation inside a
//     #pragma unroll 1 loop (2 groups/iter). Loads cannot hoist across the
//     back-edge -> max 2 generations in flight -> ~90 live regs, fits 128,
//     4 waves/SIMD. Tripwire: WRITE_SIZE >> 30MB = spills -> revert to
//     (256,1).
// ---------------------------------------------------------------------------

#define NROW 64
#define NBLK 2048            // 131072 / 64

// LDS float offsets (flat).
#define OFF_AT0  0           // AT[32][68] transposed X tile, buffer 0  (2176)
#define OFF_AT1  2176        // AT buffer 1                             (2176)
#define OFF_REDL 4352        // redL[4][64][3]  (sum, sumsq)            (768)
#define OFF_REDP 5120        // redP[4][64][9]  (6 used)                (2304)
#define OFF_EV   7424        // ev[4] wave entropy partials             (4)
#define OFF_W1B  7428        // W1bot[6][132]                           (792)
#define OFF_WC   8220        // skewed Wc: c*8 + (c>>3) + l             (1040)
#define OFF_CNT  9260        // cnt[64][7]                              (448)
#define OFF_GM   9708        // gamma[128]
#define OFF_BT   9836        // beta[128]
#define OFF_BDP  9964        // bdp[6]
#define LDS_N    9970        // 39880 B -> 4 blocks/CU

// d_out layout (floats): output[B][6], modes[B][4], lp[B], ent_mean[1]
#define OUT_MODES 786432
#define OUT_LP    1310720
#define OUT_ENT   1441792

// workspace float offsets
#define WS_WC  0             // 128*6
#define WS_BDP 768           // 6
#define WS_EP  1024          // 2048 block entropy partials

// ---------------------------------------------------------------------------
__global__ __launch_bounds__(256) void prep_kernel(
    const float* __restrict__ W2, const float* __restrict__ Wd,
    const float* __restrict__ b2, const float* __restrict__ bd,
    float* __restrict__ ws) {
  const int t = threadIdx.x;
  if (t < 128) {
    float a0 = 0.f, a1 = 0.f, a2 = 0.f, a3 = 0.f, a4 = 0.f, a5 = 0.f;
    for (int j = 0; j < 128; ++j) {
      const float w = W2[t * 128 + j];
      const float* wd = Wd + j * 6;
      a0 = fmaf(w, wd[0], a0); a1 = fmaf(w, wd[1], a1); a2 = fmaf(w, wd[2], a2);
      a3 = fmaf(w, wd[3], a3); a4 = fmaf(w, wd[4], a4); a5 = fmaf(w, wd[5], a5);
    }
    float* o = ws + WS_WC + t * 6;
    o[0] = a0; o[1] = a1; o[2] = a2; o[3] = a3; o[4] = a4; o[5] = a5;
  } else if (t < 134) {
    const int l = t - 128;
    float s = 0.f;
    for (int j = 0; j < 128; ++j) s = fmaf(b2[j], Wd[j * 6 + l], s);
    ws[WS_BDP + l] = bd[l] + s;
  }
}

// ---------------------------------------------------------------------------
__global__ __launch_bounds__(256, 2) void fused_kernel(
    const float* __restrict__ X,    // [B][256]
    const float* __restrict__ CRES, // [B][6]
    const int*   __restrict__ ACT,  // [B][4]
    const float* __restrict__ HTM,  // [16]
    const int*   __restrict__ PHA,  // [B]
    const float* __restrict__ W1,   // [262][128]
    const float* __restrict__ B1,   // [128]
    const float* __restrict__ G,    // [128]
    const float* __restrict__ BETA, // [128]
    const float* __restrict__ WS,   // workspace (Wc, bdp)
    float* __restrict__ out,
    float* __restrict__ EP) {       // [NBLK] entropy partials
  __shared__ __align__(16) float lds[LDS_N];

  const int t    = threadIdx.x;
  const int tr   = t & 15;          // GEMM: row group (4 rows each)
  const int tc   = t >> 4;          // GEMM: col group (8 cols each)
  const int r0   = tr * 4;
  const int c0   = tc * 8;
  const int wv   = t >> 6;          // wave 0..3
  const int row  = t >> 2;          // softmax layout: local row 0..63
  const int part = t & 3;           // softmax layout: 4 lanes per row
  const long grow = (long)blockIdx.x * NROW + row;

  // ---- persistent small LDS staging (visible after first barrier) ----
  if (t < 192) {                    // W1 bottom rows (output-part of concat)
    const int j = t >> 5, c = (t & 31) * 4;
    *(float4*)&lds[OFF_W1B + j * 132 + c] =
        *(const float4*)(W1 + (size_t)(256 + j) * 128 + c);
  } else {                          // zero the counts buffer (rows 0..63)
    const int rr = t - 192;
#pragma unroll
    for (int j = 0; j < 7; ++j) lds[OFF_CNT + rr * 7 + j] = 0.f;
  }
  if (t < 128) {                    // skewed Wc + gamma/beta broadcast copies
#pragma unroll
    for (int l = 0; l < 6; ++l)
      lds[OFF_WC + t * 8 + (t >> 3) + l] = WS[WS_WC + t * 6 + l];
    lds[OFF_GM + t] = G[t];
    lds[OFF_BT + t] = BETA[t];
  } else if (t < 134) {
    lds[OFF_BDP + (t - 128)] = WS[WS_BDP + (t - 128)];
  }

  // ---- GEMM helpers ----
  const float* xrow = X + (size_t)grow * 256;
  const int xoff = part * 8;

  auto load_x = [&](int th, float4& x0, float4& x1) {
    x0 = *(const float4*)(xrow + th * 32 + xoff);
    x1 = *(const float4*)(xrow + th * 32 + xoff + 4);
  };
  // AT stores: transpose X into AT[kk][row]; 4-way bank aliasing on the
  // scalar stores is unavoidable and cheap (8 stores/thread/tile).
  auto write_tile = [&](int atbase, const float4& x0, const float4& x1) {
    float* d = &lds[atbase + row];
    d[(xoff + 0) * 68] = x0.x; d[(xoff + 1) * 68] = x0.y;
    d[(xoff + 2) * 68] = x0.z; d[(xoff + 3) * 68] = x0.w;
    d[(xoff + 4) * 68] = x1.x; d[(xoff + 5) * 68] = x1.y;
    d[(xoff + 6) * 68] = x1.z; d[(xoff + 7) * 68] = x1.w;
  };

  float acc[4][8];
  {
    const float4 o0 = *(const float4*)(B1 + c0);
    const float4 o1 = *(const float4*)(B1 + c0 + 4);
    const float bi[8] = {o0.x, o0.y, o0.z, o0.w, o1.x, o1.y, o1.z, o1.w};
#pragma unroll
    for (int m = 0; m < 4; ++m)
#pragma unroll
      for (int cc = 0; cc < 8; ++cc) acc[m][cc] = bi[cc];
  }

  // B group = 2 kk-steps of this thread's 8 cols (4 float4 = 16 VGPR).
  // 16 lanes share each address -> broadcast-coalesced from L1/L2-hot W1.
  auto loadg = [&](const float* wb, int g, float4 (&Bb)[4]) {
    const float* p = wb + g * 256;
    Bb[0] = *(const float4*)(p + 0);   Bb[1] = *(const float4*)(p + 4);
    Bb[2] = *(const float4*)(p + 128); Bb[3] = *(const float4*)(p + 132);
  };
  auto compg = [&](int atbase, int g, const float4 (&Bb)[4]) {
#pragma unroll
    for (int q = 0; q < 2; ++q) {
      const float4 a4 = *(const float4*)&lds[atbase + (g * 2 + q) * 68 + r0];
      const float av[4] = {a4.x, a4.y, a4.z, a4.w};
      const float4 bl = Bb[2 * q], bh = Bb[2 * q + 1];
      const float bv[8] = {bl.x, bl.y, bl.z, bl.w, bh.x, bh.y, bh.z, bh.w};
#pragma unroll
      for (int m = 0; m < 4; ++m)
#pragma unroll
        for (int cc = 0; cc < 8; ++cc)
          acc[m][cc] = fmaf(av[m], bv[cc], acc[m][cc]);
    }
  };
  // 32 kk = 16 groups. R7: the rotation lives in a #pragma unroll 1 loop so
  // the scheduler cannot hoist loads beyond 2 in-flight buffer generations
  // (R6 lesson: straight-line code let it build 3-4 -> spilled at 128 cap).
  auto compute_tile = [&](int atbase, int ti) {
    const float* wb = W1 + (size_t)(ti * 32) * 128 + c0;
    float4 bA[4], bB[4];
    loadg(wb, 0, bA);
    loadg(wb, 1, bB);
#pragma unroll 1
    for (int g = 0; g < 14; g += 2) {
      compg(atbase, g, bA);
      loadg(wb, g + 2, bA);
      compg(atbase, g + 1, bB);
      loadg(wb, g + 3, bB);
    }
    compg(atbase, 14, bA);
    compg(atbase, 15, bB);
  };

  // ---- prologue: X tile0 -> AT0; tile1 prefetched to registers ----
  float4 xa0, xa1, xb0, xb1;
  load_x(0, xa0, xa1);
  load_x(1, xb0, xb1);
  write_tile(OFF_AT0, xa0, xa1);
  __syncthreads();                  // AT0 + small staging visible

  // ---- GEMM: 8 tiles, LDS double-buffered A, 1 barrier per tile ----
#pragma unroll 1
  for (int p = 0; p < 4; ++p) {
    write_tile(OFF_AT1, xb0, xb1);
    if (p < 3) load_x(2 * p + 2, xa0, xa1);
    compute_tile(OFF_AT0, 2 * p);
    __syncthreads();                // AT1 ready; AT0 dead
    if (p < 3) {
      write_tile(OFF_AT0, xa0, xa1);
      load_x(2 * p + 3, xb0, xb1);
    }
    compute_tile(OFF_AT1, 2 * p + 1);
    __syncthreads();                // AT0 ready for next p (or GEMM done)
  }

  // ---- post-GEMM per-row state (latency overlapped across resident waves) --
  float cr[6], cnt[6] = {0.f, 0.f, 0.f, 0.f, 0.f, 0.f};
  float m0f;                        // iteration-0 slot-0 mask
  {
    const float2* cp = (const float2*)(CRES + grow * 6);
    const float2 ca = cp[0], cb = cp[1], cc2 = cp[2];
    cr[0] = ca.x; cr[1] = ca.y; cr[2] = cb.x;
    cr[3] = cb.y; cr[4] = cc2.x; cr[5] = cc2.y;
    const float s = cr[0] + cr[1] + cr[2] + cr[3] + cr[4] + cr[5];
    m0f = (s == 0.f) ? 1.f : 0.f;
  }
  const int4 act = ((const int4*)ACT)[grow];
  const float hm = HTM[PHA[grow]];
  float lpsum = 0.f, entsum = 0.f;
  float modesf[4];

  // ---- 4 recurrent iterations (fully unrolled, static indexing only) ----
#pragma unroll
  for (int it = 0; it < 4; ++it) {
    // 1) hpre = base + counts @ W1bot
    float hp[4][8];
#pragma unroll
    for (int m = 0; m < 4; ++m)
#pragma unroll
      for (int cc = 0; cc < 8; ++cc) hp[m][cc] = acc[m][cc];
    if (it > 0) {
#pragma unroll
      for (int j = 1; j < 6; ++j) {
        const float4 w0 = *(const float4*)&lds[OFF_W1B + j * 132 + c0];
        const float4 w4 = *(const float4*)&lds[OFF_W1B + j * 132 + c0 + 4];
        const float wv8[8] = {w0.x, w0.y, w0.z, w0.w, w4.x, w4.y, w4.z, w4.w};
#pragma unroll
        for (int m = 0; m < 4; ++m) {
          const float cj = lds[OFF_CNT + (r0 + m) * 7 + j];
#pragma unroll
          for (int cc = 0; cc < 8; ++cc)
            hp[m][cc] = fmaf(cj, wv8[cc], hp[m][cc]);
        }
      }
    }

    // 2) LayerNorm stats, single pass (var = E[x^2] - mu^2)
    float mu[4], rs[4];
    {
      float sx[4], sq[4];
#pragma unroll
      for (int m = 0; m < 4; ++m) {
        float a = 0.f, b = 0.f;
#pragma unroll
        for (int cc = 0; cc < 8; ++cc) {
          a += hp[m][cc];
          b = fmaf(hp[m][cc], hp[m][cc], b);
        }
        a += __shfl_xor(a, 16, 64); a += __shfl_xor(a, 32, 64);
        b += __shfl_xor(b, 16, 64); b += __shfl_xor(b, 32, 64);
        sx[m] = a; sq[m] = b;
      }
      if ((tc & 3) == 0) {
#pragma unroll
        for (int m = 0; m < 4; ++m) {
          lds[OFF_REDL + (wv * 64 + r0 + m) * 3 + 0] = sx[m];
          lds[OFF_REDL + (wv * 64 + r0 + m) * 3 + 1] = sq[m];
        }
      }
    }
    __syncthreads();
#pragma unroll
    for (int m = 0; m < 4; ++m) {
      float a = 0.f, b = 0.f;
#pragma unroll
      for (int w = 0; w < 4; ++w) {
        a += lds[OFF_REDL + (w * 64 + r0 + m) * 3 + 0];
        b += lds[OFF_REDL + (w * 64 + r0 + m) * 3 + 1];
      }
      mu[m] = a * (1.f / 128.f);
      const float var = b * (1.f / 128.f) - mu[m] * mu[m];
      rs[m] = 1.f / sqrtf(var + 1e-5f);
    }

    // 3) relu(LN) -> partial logits. cc-outer: gamma/beta/Wc LDS reads
    //    are shared across the 4 m's (64 scalar reads/iter, broadcast).
    float pl[4][6];
#pragma unroll
    for (int m = 0; m < 4; ++m)
#pragma unroll
      for (int l = 0; l < 6; ++l) pl[m][l] = 0.f;
#pragma unroll
    for (int cc = 0; cc < 8; ++cc) {
      const float gmv = lds[OFF_GM + c0 + cc];
      const float btv = lds[OFF_BT + c0 + cc];
      const float* wp = &lds[OFF_WC + (c0 + cc) * 8 + tc];
      const float w0 = wp[0], w1 = wp[1], w2 = wp[2];
      const float w3 = wp[3], w4 = wp[4], w5 = wp[5];
#pragma unroll
      for (int m = 0; m < 4; ++m) {
        float v = fmaf((hp[m][cc] - mu[m]) * rs[m], gmv, btv);
        v = fmaxf(v, 0.f);
        pl[m][0] = fmaf(v, w0, pl[m][0]);
        pl[m][1] = fmaf(v, w1, pl[m][1]);
        pl[m][2] = fmaf(v, w2, pl[m][2]);
        pl[m][3] = fmaf(v, w3, pl[m][3]);
        pl[m][4] = fmaf(v, w4, pl[m][4]);
        pl[m][5] = fmaf(v, w5, pl[m][5]);
      }
    }
#pragma unroll
    for (int m = 0; m < 4; ++m)
#pragma unroll
      for (int l = 0; l < 6; ++l) {
        float a = pl[m][l];
        a += __shfl_xor(a, 16, 64); a += __shfl_xor(a, 32, 64);
        pl[m][l] = a;
      }
    {
      const int q = tc & 3;
#pragma unroll
      for (int mm = 0; mm < 4; ++mm)
        if (q == mm) {
#pragma unroll
          for (int l = 0; l < 6; ++l)
            lds[OFF_REDP + (wv * 64 + r0 + mm) * 9 + l] = pl[mm][l];
        }
    }
    __syncthreads();

    // 4) per-row masked log-softmax (softmax layout, 4 redundant lanes/row)
    float lg[6];
#pragma unroll
    for (int l = 0; l < 6; ++l) {
      float a = lds[OFF_REDP + row * 9 + l];
      a += lds[OFF_REDP + (64 + row) * 9 + l];
      a += lds[OFF_REDP + (128 + row) * 9 + l];
      a += lds[OFF_REDP + (192 + row) * 9 + l];
      lg[l] = a + lds[OFF_BDP + l];
    }
    float ml[6];
    ml[0] = (it == 0) ? ((m0f > 0.f) ? lg[0] : -1000000000.0f) : lg[0];
#pragma unroll
    for (int l = 1; l < 6; ++l)
      ml[l] = (cr[l] > 0.f) ? lg[l] : -1000000000.0f;
    float mx = ml[0];
    int bi = 0;
#pragma unroll
    for (int l = 1; l < 6; ++l)
      if (ml[l] > mx) { mx = ml[l]; bi = l; }   // strict > : first-max, as jnp
    modesf[it] = (float)bi;
    float sh[6], e[6], se = 0.f;
#pragma unroll
    for (int l = 0; l < 6; ++l) {
      sh[l] = ml[l] - mx;
      e[l] = __expf(sh[l]);
      se += e[l];
    }
    const float lse = __logf(se);
    const float ise = 1.f / se;
    float ent = 0.f;
#pragma unroll
    for (int l = 0; l < 6; ++l)
      ent -= (e[l] * ise) * (sh[l] - lse);   // -(p * logp); masked -> exact 0
    const int a = (it == 0) ? act.x : (it == 1) ? act.y : (it == 2) ? act.z : act.w;
    float lp = -lse;
#pragma unroll
    for (int l = 0; l < 6; ++l)
      if (l == a) lp += sh[l];
    if (it > 0) {
      const int ap = (it == 1) ? act.x : (it == 2) ? act.y : act.z;
      const float mp = (ap > 0) ? 1.f : 0.f;
      lp *= mp;
      ent *= mp;
    }
    lpsum += lp;
    entsum += ent;

    // 5) state update (exact integer arithmetic; static indexing)
#pragma unroll
    for (int l = 0; l < 6; ++l) {
      if (l == a) {
        if (l > 0) cnt[l] += 1.f;
        cr[l] = fmaxf(cr[l] - 1.f, 0.f);
      }
    }
    if (part == 0 && it < 3) {
#pragma unroll
      for (int j = 1; j < 6; ++j) lds[OFF_CNT + row * 7 + j] = cnt[j];
    }
    __syncthreads();
  }

  // ---- final outputs ----
  if (part == 0) {
    *(float2*)(out + grow * 6) = make_float2(cnt[0], cnt[1]);
  } else if (part == 1) {
    *(float2*)(out + grow * 6 + 2) = make_float2(cnt[2], cnt[3]);
  } else if (part == 2) {
    *(float2*)(out + grow * 6 + 4) = make_float2(cnt[4], cnt[5]);
  }
  if (part == 0) {
    *(float4*)(out + OUT_MODES + grow * 4) =
        make_float4(modesf[0], modesf[1], modesf[2], modesf[3]);
    out[OUT_LP + grow] = lpsum * hm;
  }
  // deterministic per-block entropy partial
  float ev = (part == 0) ? entsum * hm : 0.f;
#pragma unroll
  for (int off = 1; off < 64; off <<= 1) ev += __shfl_xor(ev, off, 64);
  if ((t & 63) == 0) lds[OFF_EV + wv] = ev;
  __syncthreads();
  if (t == 0)
    EP[blockIdx.x] =
        lds[OFF_EV] + lds[OFF_EV + 1] + lds[OFF_EV + 2] + lds[OFF_EV + 3];
}

// ---------------------------------------------------------------------------
__global__ __launch_bounds__(256) void ent_reduce(const float* __restrict__ EP,
                                                  float* __restrict__ out) {
  const int t = threadIdx.x;
  float s = 0.f;
#pragma unroll
  for (int i = 0; i < 8; ++i) s += EP[t + 256 * i];
#pragma unroll
  for (int off = 1; off < 64; off <<= 1) s += __shfl_xor(s, off, 64);
  __shared__ float w[4];
  if ((t & 63) == 0) w[t >> 6] = s;
  __syncthreads();
  if (t == 0)
    out[OUT_ENT] = (w[0] + w[1] + w[2] + w[3]) * (1.f / 131072.f);
}

// ---------------------------------------------------------------------------
extern "C" void kernel_launch(void* const* d_in, const int* in_sizes, int n_in,
                              void* d_out, int out_size, void* d_ws, size_t ws_size,
                              hipStream_t stream) {
  (void)in_sizes; (void)n_in; (void)out_size; (void)ws_size;
  const float* main_inputs = (const float*)d_in[0];
  const float* cur_res     = (const float*)d_in[1];
  const int*   actions     = (const int*)d_in[2];
  const float* htm         = (const float*)d_in[3];
  const int*   pha         = (const int*)d_in[4];
  const float* W1          = (const float*)d_in[5];
  const float* b1          = (const float*)d_in[6];
  const float* gamma       = (const float*)d_in[7];
  const float* beta        = (const float*)d_in[8];
  const float* W2          = (const float*)d_in[9];
  const float* b2          = (const float*)d_in[10];
  const float* Wd          = (const float*)d_in[11];
  const float* bd          = (const float*)d_in[12];
  float* out = (float*)d_out;
  float* ws  = (float*)d_ws;

  prep_kernel<<<1, 256, 0, stream>>>(W2, Wd, b2, bd, ws);
  fused_kernel<<<NBLK, 256, 0, stream>>>(main_inputs, cur_res, actions, htm,
                                         pha, W1, b1, gamma, beta, ws, out,
                                         ws + WS_EP);
  ent_reduce<<<1, 256, 0, stream>>>(ws + WS_EP, out);
}

// Round 8
// 397.675 us; speedup vs baseline: 2.2310x; 1.0195x over previous
//
#include <hip/hip_runtime.h>
#include <hip/hip_bf16.h>
#include <cstdint>

// ---------------------------------------------------------------------------
// RecurrentResourceActionHead — fused single-pass implementation.
//
// Key algebra:
//  * x = [main_inputs, output]; x@W1 = main@W1[0:256] (iteration-invariant,
//    computed ONCE) + counts@W1[256:262] (rank<=5 correction per iteration).
//  * h is unobserved: logits = relu(LN)@(W2@Wd) + (b2@Wd + bd). W2@Wd (128x6)
//    precomputed by prep_kernel.
//
// R4: (256,2) caps VGPR at 128; 248-reg demand spilled 2.4 GB.
// R5: (256,1) -> 248 VGPR, no spills, 2 waves/SIMD, latency-bound 386us.
// R6: fully-unrolled inner loop -> scheduler built 3-4 in-flight buffer
//     generations -> spilled at the 128 cap. Schedule sets pressure.
// R7: unroll-1 pinned 2-buffer rotation -> 108 VGPR, no spills, 4 waves/SIMD,
//     253us. VALUBusy 51% -> still ~60% stall; issue-model floor ~90us.
// R8: ONE variable: 3-buffer B rotation (prefetch distance ~2 compg ~1000+
//     SIMD-cyc at 4-way interleave, covers L2-miss/HBM-class latency).
//     VGPR 108->~124, still under 128. Tripwire: WRITE_SIZE >> 30MB = spill
//     -> revert. If dur unchanged ~250 and no spills: latency theory wrong,
//     go to LDS-staged-B next.
// ---------------------------------------------------------------------------

#define NROW 64
#define NBLK 2048            // 131072 / 64

// LDS float offsets (flat).
#define OFF_AT0  0           // AT[32][68] transposed X tile, buffer 0  (2176)
#define OFF_AT1  2176        // AT buffer 1                             (2176)
#define OFF_REDL 4352        // redL[4][64][3]  (sum, sumsq)            (768)
#define OFF_REDP 5120        // redP[4][64][9]  (6 used)                (2304)
#define OFF_EV   7424        // ev[4] wave entropy partials             (4)
#define OFF_W1B  7428        // W1bot[6][132]                           (792)
#define OFF_WC   8220        // skewed Wc: c*8 + (c>>3) + l             (1040)
#define OFF_CNT  9260        // cnt[64][7]                              (448)
#define OFF_GM   9708        // gamma[128]
#define OFF_BT   9836        // beta[128]
#define OFF_BDP  9964        // bdp[6]
#define LDS_N    9970        // 39880 B -> 4 blocks/CU

// d_out layout (floats): output[B][6], modes[B][4], lp[B], ent_mean[1]
#define OUT_MODES 786432
#define OUT_LP    1310720
#define OUT_ENT   1441792

// workspace float offsets
#define WS_WC  0             // 128*6
#define WS_BDP 768           // 6
#define WS_EP  1024          // 2048 block entropy partials

// ---------------------------------------------------------------------------
__global__ __launch_bounds__(256) void prep_kernel(
    const float* __restrict__ W2, const float* __restrict__ Wd,
    const float* __restrict__ b2, const float* __restrict__ bd,
    float* __restrict__ ws) {
  const int t = threadIdx.x;
  if (t < 128) {
    float a0 = 0.f, a1 = 0.f, a2 = 0.f, a3 = 0.f, a4 = 0.f, a5 = 0.f;
    for (int j = 0; j < 128; ++j) {
      const float w = W2[t * 128 + j];
      const float* wd = Wd + j * 6;
      a0 = fmaf(w, wd[0], a0); a1 = fmaf(w, wd[1], a1); a2 = fmaf(w, wd[2], a2);
      a3 = fmaf(w, wd[3], a3); a4 = fmaf(w, wd[4], a4); a5 = fmaf(w, wd[5], a5);
    }
    float* o = ws + WS_WC + t * 6;
    o[0] = a0; o[1] = a1; o[2] = a2; o[3] = a3; o[4] = a4; o[5] = a5;
  } else if (t < 134) {
    const int l = t - 128;
    float s = 0.f;
    for (int j = 0; j < 128; ++j) s = fmaf(b2[j], Wd[j * 6 + l], s);
    ws[WS_BDP + l] = bd[l] + s;
  }
}

// ---------------------------------------------------------------------------
__global__ __launch_bounds__(256, 2) void fused_kernel(
    const float* __restrict__ X,    // [B][256]
    const float* __restrict__ CRES, // [B][6]
    const int*   __restrict__ ACT,  // [B][4]
    const float* __restrict__ HTM,  // [16]
    const int*   __restrict__ PHA,  // [B]
    const float* __restrict__ W1,   // [262][128]
    const float* __restrict__ B1,   // [128]
    const float* __restrict__ G,    // [128]
    const float* __restrict__ BETA, // [128]
    const float* __restrict__ WS,   // workspace (Wc, bdp)
    float* __restrict__ out,
    float* __restrict__ EP) {       // [NBLK] entropy partials
  __shared__ __align__(16) float lds[LDS_N];

  const int t    = threadIdx.x;
  const int tr   = t & 15;          // GEMM: row group (4 rows each)
  const int tc   = t >> 4;          // GEMM: col group (8 cols each)
  const int r0   = tr * 4;
  const int c0   = tc * 8;
  const int wv   = t >> 6;          // wave 0..3
  const int row  = t >> 2;          // softmax layout: local row 0..63
  const int part = t & 3;           // softmax layout: 4 lanes per row
  const long grow = (long)blockIdx.x * NROW + row;

  // ---- persistent small LDS staging (visible after first barrier) ----
  if (t < 192) {                    // W1 bottom rows (output-part of concat)
    const int j = t >> 5, c = (t & 31) * 4;
    *(float4*)&lds[OFF_W1B + j * 132 + c] =
        *(const float4*)(W1 + (size_t)(256 + j) * 128 + c);
  } else {                          // zero the counts buffer (rows 0..63)
    const int rr = t - 192;
#pragma unroll
    for (int j = 0; j < 7; ++j) lds[OFF_CNT + rr * 7 + j] = 0.f;
  }
  if (t < 128) {                    // skewed Wc + gamma/beta broadcast copies
#pragma unroll
    for (int l = 0; l < 6; ++l)
      lds[OFF_WC + t * 8 + (t >> 3) + l] = WS[WS_WC + t * 6 + l];
    lds[OFF_GM + t] = G[t];
    lds[OFF_BT + t] = BETA[t];
  } else if (t < 134) {
    lds[OFF_BDP + (t - 128)] = WS[WS_BDP + (t - 128)];
  }

  // ---- GEMM helpers ----
  const float* xrow = X + (size_t)grow * 256;
  const int xoff = part * 8;

  auto load_x = [&](int th, float4& x0, float4& x1) {
    x0 = *(const float4*)(xrow + th * 32 + xoff);
    x1 = *(const float4*)(xrow + th * 32 + xoff + 4);
  };
  // AT stores: transpose X into AT[kk][row]; 4-way bank aliasing on the
  // scalar stores is unavoidable and cheap (8 stores/thread/tile).
  auto write_tile = [&](int atbase, const float4& x0, const float4& x1) {
    float* d = &lds[atbase + row];
    d[(xoff + 0) * 68] = x0.x; d[(xoff + 1) * 68] = x0.y;
    d[(xoff + 2) * 68] = x0.z; d[(xoff + 3) * 68] = x0.w;
    d[(xoff + 4) * 68] = x1.x; d[(xoff + 5) * 68] = x1.y;
    d[(xoff + 6) * 68] = x1.z; d[(xoff + 7) * 68] = x1.w;
  };

  float acc[4][8];
  {
    const float4 o0 = *(const float4*)(B1 + c0);
    const float4 o1 = *(const float4*)(B1 + c0 + 4);
    const float bi[8] = {o0.x, o0.y, o0.z, o0.w, o1.x, o1.y, o1.z, o1.w};
#pragma unroll
    for (int m = 0; m < 4; ++m)
#pragma unroll
      for (int cc = 0; cc < 8; ++cc) acc[m][cc] = bi[cc];
  }

  // B group = 2 kk-steps of this thread's 8 cols (4 float4 = 16 VGPR).
  // 16 lanes share each address -> broadcast-coalesced from L1/L2-hot W1.
  auto loadg = [&](const float* wb, int g, float4 (&Bb)[4]) {
    const float* p = wb + g * 256;
    Bb[0] = *(const float4*)(p + 0);   Bb[1] = *(const float4*)(p + 4);
    Bb[2] = *(const float4*)(p + 128); Bb[3] = *(const float4*)(p + 132);
  };
  auto compg = [&](int atbase, int g, const float4 (&Bb)[4]) {
#pragma unroll
    for (int q = 0; q < 2; ++q) {
      const float4 a4 = *(const float4*)&lds[atbase + (g * 2 + q) * 68 + r0];
      const float av[4] = {a4.x, a4.y, a4.z, a4.w};
      const float4 bl = Bb[2 * q], bh = Bb[2 * q + 1];
      const float bv[8] = {bl.x, bl.y, bl.z, bl.w, bh.x, bh.y, bh.z, bh.w};
#pragma unroll
      for (int m = 0; m < 4; ++m)
#pragma unroll
        for (int cc = 0; cc < 8; ++cc)
          acc[m][cc] = fmaf(av[m], bv[cc], acc[m][cc]);
    }
  };
  // 32 kk = 16 groups. R8: THREE-buffer rotation in a #pragma unroll 1 loop
  // (loads cannot hoist past the back-edge -> exactly 3 generations in
  // flight). Prefetch distance ~2 compg issued ahead of use.
  auto compute_tile = [&](int atbase, int ti) {
    const float* wb = W1 + (size_t)(ti * 32) * 128 + c0;
    float4 bA[4], bB[4], bC[4];
    loadg(wb, 0, bA);
    loadg(wb, 1, bB);
    loadg(wb, 2, bC);
#pragma unroll 1
    for (int g = 0; g < 12; g += 3) {
      compg(atbase, g + 0, bA); loadg(wb, g + 3, bA);
      compg(atbase, g + 1, bB); loadg(wb, g + 4, bB);
      compg(atbase, g + 2, bC); loadg(wb, g + 5, bC);
    }
    compg(atbase, 12, bA); loadg(wb, 15, bA);
    compg(atbase, 13, bB);
    compg(atbase, 14, bC);
    compg(atbase, 15, bA);
  };

  // ---- prologue: X tile0 -> AT0; tile1 prefetched to registers ----
  float4 xa0, xa1, xb0, xb1;
  load_x(0, xa0, xa1);
  load_x(1, xb0, xb1);
  write_tile(OFF_AT0, xa0, xa1);
  __syncthreads();                  // AT0 + small staging visible

  // ---- GEMM: 8 tiles, LDS double-buffered A, 1 barrier per tile ----
#pragma unroll 1
  for (int p = 0; p < 4; ++p) {
    write_tile(OFF_AT1, xb0, xb1);
    if (p < 3) load_x(2 * p + 2, xa0, xa1);
    compute_tile(OFF_AT0, 2 * p);
    __syncthreads();                // AT1 ready; AT0 dead
    if (p < 3) {
      write_tile(OFF_AT0, xa0, xa1);
      load_x(2 * p + 3, xb0, xb1);
    }
    compute_tile(OFF_AT1, 2 * p + 1);
    __syncthreads();                // AT0 ready for next p (or GEMM done)
  }

  // ---- post-GEMM per-row state (latency overlapped across resident waves) --
  float cr[6], cnt[6] = {0.f, 0.f, 0.f, 0.f, 0.f, 0.f};
  float m0f;                        // iteration-0 slot-0 mask
  {
    const float2* cp = (const float2*)(CRES + grow * 6);
    const float2 ca = cp[0], cb = cp[1], cc2 = cp[2];
    cr[0] = ca.x; cr[1] = ca.y; cr[2] = cb.x;
    cr[3] = cb.y; cr[4] = cc2.x; cr[5] = cc2.y;
    const float s = cr[0] + cr[1] + cr[2] + cr[3] + cr[4] + cr[5];
    m0f = (s == 0.f) ? 1.f : 0.f;
  }
  const int4 act = ((const int4*)ACT)[grow];
  const float hm = HTM[PHA[grow]];
  float lpsum = 0.f, entsum = 0.f;
  float modesf[4];

  // ---- 4 recurrent iterations (fully unrolled, static indexing only) ----
#pragma unroll
  for (int it = 0; it < 4; ++it) {
    // 1) hpre = base + counts @ W1bot
    float hp[4][8];
#pragma unroll
    for (int m = 0; m < 4; ++m)
#pragma unroll
      for (int cc = 0; cc < 8; ++cc) hp[m][cc] = acc[m][cc];
    if (it > 0) {
#pragma unroll
      for (int j = 1; j < 6; ++j) {
        const float4 w0 = *(const float4*)&lds[OFF_W1B + j * 132 + c0];
        const float4 w4 = *(const float4*)&lds[OFF_W1B + j * 132 + c0 + 4];
        const float wv8[8] = {w0.x, w0.y, w0.z, w0.w, w4.x, w4.y, w4.z, w4.w};
#pragma unroll
        for (int m = 0; m < 4; ++m) {
          const float cj = lds[OFF_CNT + (r0 + m) * 7 + j];
#pragma unroll
          for (int cc = 0; cc < 8; ++cc)
            hp[m][cc] = fmaf(cj, wv8[cc], hp[m][cc]);
        }
      }
    }

    // 2) LayerNorm stats, single pass (var = E[x^2] - mu^2)
    float mu[4], rs[4];
    {
      float sx[4], sq[4];
#pragma unroll
      for (int m = 0; m < 4; ++m) {
        float a = 0.f, b = 0.f;
#pragma unroll
        for (int cc = 0; cc < 8; ++cc) {
          a += hp[m][cc];
          b = fmaf(hp[m][cc], hp[m][cc], b);
        }
        a += __shfl_xor(a, 16, 64); a += __shfl_xor(a, 32, 64);
        b += __shfl_xor(b, 16, 64); b += __shfl_xor(b, 32, 64);
        sx[m] = a; sq[m] = b;
      }
      if ((tc & 3) == 0) {
#pragma unroll
        for (int m = 0; m < 4; ++m) {
          lds[OFF_REDL + (wv * 64 + r0 + m) * 3 + 0] = sx[m];
          lds[OFF_REDL + (wv * 64 + r0 + m) * 3 + 1] = sq[m];
        }
      }
    }
    __syncthreads();
#pragma unroll
    for (int m = 0; m < 4; ++m) {
      float a = 0.f, b = 0.f;
#pragma unroll
      for (int w = 0; w < 4; ++w) {
        a += lds[OFF_REDL + (w * 64 + r0 + m) * 3 + 0];
        b += lds[OFF_REDL + (w * 64 + r0 + m) * 3 + 1];
      }
      mu[m] = a * (1.f / 128.f);
      const float var = b * (1.f / 128.f) - mu[m] * mu[m];
      rs[m] = 1.f / sqrtf(var + 1e-5f);
    }

    // 3) relu(LN) -> partial logits. cc-outer: gamma/beta/Wc LDS reads
    //    are shared across the 4 m's (64 scalar reads/iter, broadcast).
    float pl[4][6];
#pragma unroll
    for (int m = 0; m < 4; ++m)
#pragma unroll
      for (int l = 0; l < 6; ++l) pl[m][l] = 0.f;
#pragma unroll
    for (int cc = 0; cc < 8; ++cc) {
      const float gmv = lds[OFF_GM + c0 + cc];
      const float btv = lds[OFF_BT + c0 + cc];
      const float* wp = &lds[OFF_WC + (c0 + cc) * 8 + tc];
      const float w0 = wp[0], w1 = wp[1], w2 = wp[2];
      const float w3 = wp[3], w4 = wp[4], w5 = wp[5];
#pragma unroll
      for (int m = 0; m < 4; ++m) {
        float v = fmaf((hp[m][cc] - mu[m]) * rs[m], gmv, btv);
        v = fmaxf(v, 0.f);
        pl[m][0] = fmaf(v, w0, pl[m][0]);
        pl[m][1] = fmaf(v, w1, pl[m][1]);
        pl[m][2] = fmaf(v, w2, pl[m][2]);
        pl[m][3] = fmaf(v, w3, pl[m][3]);
        pl[m][4] = fmaf(v, w4, pl[m][4]);
        pl[m][5] = fmaf(v, w5, pl[m][5]);
      }
    }
#pragma unroll
    for (int m = 0; m < 4; ++m)
#pragma unroll
      for (int l = 0; l < 6; ++l) {
        float a = pl[m][l];
        a += __shfl_xor(a, 16, 64); a += __shfl_xor(a, 32, 64);
        pl[m][l] = a;
      }
    {
      const int q = tc & 3;
#pragma unroll
      for (int mm = 0; mm < 4; ++mm)
        if (q == mm) {
#pragma unroll
          for (int l = 0; l < 6; ++l)
            lds[OFF_REDP + (wv * 64 + r0 + mm) * 9 + l] = pl[mm][l];
        }
    }
    __syncthreads();

    // 4) per-row masked log-softmax (softmax layout, 4 redundant lanes/row)
    float lg[6];
#pragma unroll
    for (int l = 0; l < 6; ++l) {
      float a = lds[OFF_REDP + row * 9 + l];
      a += lds[OFF_REDP + (64 + row) * 9 + l];
      a += lds[OFF_REDP + (128 + row) * 9 + l];
      a += lds[OFF_REDP + (192 + row) * 9 + l];
      lg[l] = a + lds[OFF_BDP + l];
    }
    float ml[6];
    ml[0] = (it == 0) ? ((m0f > 0.f) ? lg[0] : -1000000000.0f) : lg[0];
#pragma unroll
    for (int l = 1; l < 6; ++l)
      ml[l] = (cr[l] > 0.f) ? lg[l] : -1000000000.0f;
    float mx = ml[0];
    int bi = 0;
#pragma unroll
    for (int l = 1; l < 6; ++l)
      if (ml[l] > mx) { mx = ml[l]; bi = l; }   // strict > : first-max, as jnp
    modesf[it] = (float)bi;
    float sh[6], e[6], se = 0.f;
#pragma unroll
    for (int l = 0; l < 6; ++l) {
      sh[l] = ml[l] - mx;
      e[l] = __expf(sh[l]);
      se += e[l];
    }
    const float lse = __logf(se);
    const float ise = 1.f / se;
    float ent = 0.f;
#pragma unroll
    for (int l = 0; l < 6; ++l)
      ent -= (e[l] * ise) * (sh[l] - lse);   // -(p * logp); masked -> exact 0
    const int a = (it == 0) ? act.x : (it == 1) ? act.y : (it == 2) ? act.z : act.w;
    float lp = -lse;
#pragma unroll
    for (int l = 0; l < 6; ++l)
      if (l == a) lp += sh[l];
    if (it > 0) {
      const int ap = (it == 1) ? act.x : (it == 2) ? act.y : act.z;
      const float mp = (ap > 0) ? 1.f : 0.f;
      lp *= mp;
      ent *= mp;
    }
    lpsum += lp;
    entsum += ent;

    // 5) state update (exact integer arithmetic; static indexing)
#pragma unroll
    for (int l = 0; l < 6; ++l) {
      if (l == a) {
        if (l > 0) cnt[l] += 1.f;
        cr[l] = fmaxf(cr[l] - 1.f, 0.f);
      }
    }
    if (part == 0 && it < 3) {
#pragma unroll
      for (int j = 1; j < 6; ++j) lds[OFF_CNT + row * 7 + j] = cnt[j];
    }
    __syncthreads();
  }

  // ---- final outputs ----
  if (part == 0) {
    *(float2*)(out + grow * 6) = make_float2(cnt[0], cnt[1]);
  } else if (part == 1) {
    *(float2*)(out + grow * 6 + 2) = make_float2(cnt[2], cnt[3]);
  } else if (part == 2) {
    *(float2*)(out + grow * 6 + 4) = make_float2(cnt[4], cnt[5]);
  }
  if (part == 0) {
    *(float4*)(out + OUT_MODES + grow * 4) =
        make_float4(modesf[0], modesf[1], modesf[2], modesf[3]);
    out[OUT_LP + grow] = lpsum * hm;
  }
  // deterministic per-block entropy partial
  float ev = (part == 0) ? entsum * hm : 0.f;
#pragma unroll
  for (int off = 1; off < 64; off <<= 1) ev += __shfl_xor(ev, off, 64);
  if ((t & 63) == 0) lds[OFF_EV + wv] = ev;
  __syncthreads();
  if (t == 0)
    EP[blockIdx.x] =
        lds[OFF_EV] + lds[OFF_EV + 1] + lds[OFF_EV + 2] + lds[OFF_EV + 3];
}

// ---------------------------------------------------------------------------
__global__ __launch_bounds__(256) void ent_reduce(const float* __restrict__ EP,
                                                  float* __restrict__ out) {
  const int t = threadIdx.x;
  float s = 0.f;
#pragma unroll
  for (int i = 0; i < 8; ++i) s += EP[t + 256 * i];
#pragma unroll
  for (int off = 1; off < 64; off <<= 1) s += __shfl_xor(s, off, 64);
  __shared__ float w[4];
  if ((t & 63) == 0) w[t >> 6] = s;
  __syncthreads();
  if (t == 0)
    out[OUT_ENT] = (w[0] + w[1] + w[2] + w[3]) * (1.f / 131072.f);
}

// ---------------------------------------------------------------------------
extern "C" void kernel_launch(void* const* d_in, const int* in_sizes, int n_in,
                              void* d_out, int out_size, void* d_ws, size_t ws_size,
                              hipStream_t stream) {
  (void)in_sizes; (void)n_in; (void)out_size; (void)ws_size;
  const float* main_inputs = (const float*)d_in[0];
  const float* cur_res     = (const float*)d_in[1];
  const int*   actions     = (const int*)d_in[2];
  const float* htm         = (const float*)d_in[3];
  const int*   pha         = (const int*)d_in[4];
  const float* W1          = (const float*)d_in[5];
  const float* b1          = (const float*)d_in[6];
  const float* gamma       = (const float*)d_in[7];
  const float* beta        = (const float*)d_in[8];
  const float* W2          = (const float*)d_in[9];
  const float* b2          = (const float*)d_in[10];
  const float* Wd          = (const float*)d_in[11];
  const float* bd          = (const float*)d_in[12];
  float* out = (float*)d_out;
  float* ws  = (float*)d_ws;

  prep_kernel<<<1, 256, 0, stream>>>(W2, Wd, b2, bd, ws);
  fused_kernel<<<NBLK, 256, 0, stream>>>(main_inputs, cur_res, actions, htm,
                                         pha, W1, b1, gamma, beta, ws, out,
                                         ws + WS_EP);
  ent_reduce<<<1, 256, 0, stream>>>(ws + WS_EP, out);
}